// Round 14
// baseline (122.073 us; speedup 1.0000x reference)
//
#include <hip/hip_runtime.h>
#include <math.h>

static constexpr int kH = 1024;
static constexpr int kV = 50257;
static constexpr int kS = 4096;
static constexpr int kLogABlocks = (kV + 3) / 4;   // 12565 (4 rows/block)
static constexpr int kLogBBlocks = 2048;           // wave-strided, 8192 waves
static constexpr float kEShift = 30.f;             // uniform softmax shift

__device__ __forceinline__ float wred_sum(float v) {
#pragma unroll
  for (int o = 32; o > 0; o >>= 1) v += __shfl_down(v, o, 64);
  return v;
}
__device__ __forceinline__ float wred_sum_all(float v) {
#pragma unroll
  for (int o = 32; o > 0; o >>= 1) v += __shfl_xor(v, o, 64);
  return v;
}

// One block per output element i of the GRU cell.
// If tok != nullptr: x = [emb[tok[0]], xb] (width 2H), else x = xa (width H).
// Blocks 0..8 zero the atomic accumulators zu/zc/zz when zu != nullptr.
__global__ __launch_bounds__(256) void gru_kernel(
    const int* __restrict__ tok, const float* __restrict__ emb,
    const float* __restrict__ xa, const float* __restrict__ xb,
    const float* __restrict__ hprev,
    const float* __restrict__ Wih, const float* __restrict__ Whh,
    const float* __restrict__ bih, const float* __restrict__ bhh,
    float* __restrict__ hout, float* __restrict__ hout2,
    float* __restrict__ zu, float* __restrict__ zc, float* __restrict__ zz) {
  const int i = blockIdx.x;
  const int t = threadIdx.x;
  const int lane = t & 63, wid = t >> 6;

  if (zu) {
    if (i < 4) zu[i * 256 + t] = 0.f;
    else if (i < 8) zc[(i - 4) * 256 + t] = 0.f;
    else if (i == 8 && t == 0) zz[0] = 0.f;
  }

  const float* xrow = tok ? (emb + (size_t)tok[0] * kH) : xa;
  const int nk4 = tok ? 512 : 256;         // float4 count of x
  const size_t xw = tok ? (size_t)(2 * kH) : (size_t)kH;

  const float4* X0 = (const float4*)xrow;
  const float4* X1 = (const float4*)xb;
  const float4* Wr = (const float4*)(Wih + (size_t)i * xw);
  const float4* Wz = (const float4*)(Wih + (size_t)(kH + i) * xw);
  const float4* Wn = (const float4*)(Wih + (size_t)(2 * kH + i) * xw);
  const float4* Ur = (const float4*)(Whh + (size_t)i * kH);
  const float4* Uz = (const float4*)(Whh + (size_t)(kH + i) * kH);
  const float4* Un = (const float4*)(Whh + (size_t)(2 * kH + i) * kH);
  const float4* Hp = (const float4*)hprev;

  float ar = 0.f, az = 0.f, an = 0.f, br = 0.f, bz = 0.f, bn = 0.f;
  for (int k = t; k < nk4; k += 256) {
    const float4 x = (k < 256) ? X0[k] : X1[k - 256];
    float4 w;
    w = Wr[k]; ar += w.x * x.x + w.y * x.y + w.z * x.z + w.w * x.w;
    w = Wz[k]; az += w.x * x.x + w.y * x.y + w.z * x.z + w.w * x.w;
    w = Wn[k]; an += w.x * x.x + w.y * x.y + w.z * x.z + w.w * x.w;
  }
  {
    const float4 h = Hp[t];
    float4 w;
    w = Ur[t]; br += w.x * h.x + w.y * h.y + w.z * h.z + w.w * h.w;
    w = Uz[t]; bz += w.x * h.x + w.y * h.y + w.z * h.z + w.w * h.w;
    w = Un[t]; bn += w.x * h.x + w.y * h.y + w.z * h.z + w.w * h.w;
  }
  ar = wred_sum(ar); az = wred_sum(az); an = wred_sum(an);
  br = wred_sum(br); bz = wred_sum(bz); bn = wred_sum(bn);
  __shared__ float red[6][4];
  if (lane == 0) {
    red[0][wid] = ar; red[1][wid] = az; red[2][wid] = an;
    red[3][wid] = br; red[4][wid] = bz; red[5][wid] = bn;
  }
  __syncthreads();
  if (t == 0) {
    const float s0 = red[0][0] + red[0][1] + red[0][2] + red[0][3];
    const float s1 = red[1][0] + red[1][1] + red[1][2] + red[1][3];
    const float s2 = red[2][0] + red[2][1] + red[2][2] + red[2][3];
    const float s3 = red[3][0] + red[3][1] + red[3][2] + red[3][3];
    const float s4 = red[4][0] + red[4][1] + red[4][2] + red[4][3];
    const float s5 = red[5][0] + red[5][1] + red[5][2] + red[5][3];
    const float r = 1.f / (1.f + expf(-((s0 + bih[i]) + (s3 + bhh[i]))));
    const float z = 1.f / (1.f + expf(-((s1 + bih[kH + i]) + (s4 + bhh[kH + i]))));
    const float n = tanhf((s2 + bih[2 * kH + i]) + r * (s5 + bhh[2 * kH + i]));
    const float h = (1.f - z) * n + z * hprev[i];
    hout[i] = h;
    hout2[i] = h;
  }
}

// Fused: blocks 0..127 compute u = attn_W^T h1 (atomics into u);
// blocks 128.. compute logitsA[v] = dot(out_W[v, 0:H], h1) + out_b[v],
// 4 consecutive rows per block, one wave per row (one-shot, contiguous).
__global__ __launch_bounds__(256) void attnu_logitsA_kernel(
    const float* __restrict__ attn_W, const float* __restrict__ h1,
    float* __restrict__ u, const float* __restrict__ out_W,
    const float* __restrict__ out_b, float* __restrict__ logits) {
  const int b = blockIdx.x;
  const int t = threadIdx.x;
  if (b < 128) {
    const int j0 = b * 8;
    const float4* W4 = (const float4*)attn_W;
    float4 acc = make_float4(0.f, 0.f, 0.f, 0.f);
#pragma unroll
    for (int j = j0; j < j0 + 8; ++j) {
      const float hj = h1[j];
      const float4 w = W4[(size_t)j * 256 + t];
      acc.x += hj * w.x; acc.y += hj * w.y;
      acc.z += hj * w.z; acc.w += hj * w.w;
    }
    atomicAdd(&u[4 * t + 0], acc.x);
    atomicAdd(&u[4 * t + 1], acc.y);
    atomicAdd(&u[4 * t + 2], acc.z);
    atomicAdd(&u[4 * t + 3], acc.w);
    return;
  }
  const int lane = t & 63;
  const int v = (b - 128) * 4 + (t >> 6);
  if (v >= kV) return;
  const float4* W = (const float4*)(out_W + (size_t)v * (2 * kH));
  const float4* X0 = (const float4*)h1;
  float acc = 0.f;
#pragma unroll
  for (int k = lane; k < 256; k += 64) {
    const float4 w = W[k];
    const float4 x = X0[k];
    acc += w.x * x.x + w.y * x.y + w.z * x.z + w.w * x.w;
  }
  acc = wred_sum(acc);
  if (lane == 0) logits[v] = acc + out_b[v];
}

// Fused attention: 256 blocks x 4 waves x 4 rows. Per row s:
//   e_s = dot(enc[s], u);  w_s = exp(e_s - kEShift)   (uniform shift -> exact
//   cancellation in normalization; no global max pass needed)
// Reuses the enc row already in registers to accumulate unnormalized
// ctx += w_s * enc[s] (LDS-staged per wave, then global atomics) and Z.
__global__ __launch_bounds__(256) void attn_fused_kernel(
    const float* __restrict__ enc, const float* __restrict__ u,
    float* __restrict__ wexp, float* __restrict__ ctx, float* __restrict__ Z) {
  const int b = blockIdx.x;
  const int t = threadIdx.x;
  const int lane = t & 63, wid = t >> 6;
  __shared__ float cacc[4][kH];  // 16 KB: per-wave unnormalized ctx partials
  __shared__ float zred[4];

  const float4* U4 = (const float4*)u;
  float4 u4[4];
#pragma unroll
  for (int j = 0; j < 4; ++j) u4[j] = U4[lane + 64 * j];

  float4 c4[4];
#pragma unroll
  for (int j = 0; j < 4; ++j) c4[j] = make_float4(0.f, 0.f, 0.f, 0.f);
  float zp = 0.f;
  const int s0 = b * 16 + wid * 4;
#pragma unroll
  for (int r = 0; r < 4; ++r) {
    const int s = s0 + r;
    const float4* E = (const float4*)(enc + (size_t)s * kH);
    float4 e4[4];
    float acc = 0.f;
#pragma unroll
    for (int j = 0; j < 4; ++j) {
      e4[j] = E[lane + 64 * j];
      acc += e4[j].x * u4[j].x + e4[j].y * u4[j].y + e4[j].z * u4[j].z +
             e4[j].w * u4[j].w;
    }
    acc = wred_sum_all(acc);
    const float w = expf(acc - kEShift);
    if (lane == 0) { wexp[s] = w; zp += w; }
#pragma unroll
    for (int j = 0; j < 4; ++j) {
      c4[j].x += w * e4[j].x; c4[j].y += w * e4[j].y;
      c4[j].z += w * e4[j].z; c4[j].w += w * e4[j].w;
    }
  }
#pragma unroll
  for (int j = 0; j < 4; ++j)
    ((float4*)&cacc[wid][0])[lane + 64 * j] = c4[j];
  if (lane == 0) zred[wid] = zp;
  __syncthreads();
#pragma unroll
  for (int j = 0; j < 4; ++j) {
    const int idx = t + 256 * j;
    const float vsum =
        cacc[0][idx] + cacc[1][idx] + cacc[2][idx] + cacc[3][idx];
    atomicAdd(&ctx[idx], vsum);
  }
  if (t == 0) atomicAdd(Z, zred[0] + zred[1] + zred[2] + zred[3]);
}

// logitsB: logits[v] += invZ * dot(out_W[v, H:2H], ctx_unnorm), wave-strided
// rows (~6 per wave), online LSE per wave -> one partial per block.
__global__ __launch_bounds__(256) void logitsB_kernel(
    const float* __restrict__ out_W, const float* __restrict__ ctx,
    const float* __restrict__ Z, float* __restrict__ logits,
    float* __restrict__ part) {
  const int b = blockIdx.x;
  const int t = threadIdx.x;
  const int lane = t & 63, wid = t >> 6;
  __shared__ float red[2][4];

  const float invZ = 1.f / Z[0];
  const float4* X1 = (const float4*)ctx;
  float4 x1[4];
#pragma unroll
  for (int j = 0; j < 4; ++j) x1[j] = X1[lane + 64 * j];

  float lm = -INFINITY, ls = 0.f;
  for (int v = b * 4 + wid; v < kV; v += kLogBBlocks * 4) {
    const float4* W = (const float4*)(out_W + (size_t)v * (2 * kH)) + 256;
    float acc1 = 0.f;
#pragma unroll
    for (int j = 0; j < 4; ++j) {
      const float4 w = W[lane + 64 * j];
      acc1 += w.x * x1[j].x + w.y * x1[j].y + w.z * x1[j].z + w.w * x1[j].w;
    }
    const float acc = wred_sum(acc1);
    if (lane == 0) {
      const float val = logits[v] + invZ * acc;
      logits[v] = val;
      const float M2 = fmaxf(lm, val);
      ls = ls * expf(lm - M2) + expf(val - M2);
      lm = M2;
    }
  }
  if (lane == 0) { red[0][wid] = lm; red[1][wid] = ls; }
  __syncthreads();
  if (t == 0) {
    float m = red[0][0], s = red[1][0];
#pragma unroll
    for (int w = 1; w < 4; ++w) {
      const float M2 = fmaxf(m, red[0][w]);
      s = s * expf(m - M2) + red[1][w] * expf(red[0][w] - M2);
      m = M2;
    }
    part[2 * b] = m;
    part[2 * b + 1] = s;
  }
}

// finalize: each block redundantly merges the 2048 LSE partials (16 KB, L2),
// normalizes its 256 logits; blocks 0..3 write o_ctx = ctx*invZ;
// blocks 4..19 write o_attn = wexp*invZ.
__global__ __launch_bounds__(256) void finalize_kernel(
    float* __restrict__ logits, const float* __restrict__ part,
    const float* __restrict__ ctx_ws, const float* __restrict__ wexp,
    const float* __restrict__ Z, float* __restrict__ o_ctx,
    float* __restrict__ o_attn) {
  const int b = blockIdx.x;
  const int t = threadIdx.x;
  const int lane = t & 63, wid = t >> 6;
  __shared__ float red[2][4];

  float m = -INFINITY, s = 0.f;
  for (int i = t; i < kLogBBlocks; i += 256) {
    const float bm = part[2 * i], bs = part[2 * i + 1];
    const float M2 = fmaxf(m, bm);
    s = s * expf(m - M2) + bs * expf(bm - M2);
    m = M2;
  }
#pragma unroll
  for (int o = 32; o > 0; o >>= 1) {
    const float m2 = __shfl_down(m, o, 64);
    const float s2 = __shfl_down(s, o, 64);
    const float M2 = fmaxf(m, m2);
    s = s * expf(m - M2) + s2 * expf(m2 - M2);
    m = M2;
  }
  if (lane == 0) { red[0][wid] = m; red[1][wid] = s; }
  __syncthreads();
  float M = red[0][0], S = red[1][0];
#pragma unroll
  for (int w = 1; w < 4; ++w) {
    const float M2 = fmaxf(M, red[0][w]);
    S = S * expf(M - M2) + red[1][w] * expf(red[0][w] - M2);
    M = M2;
  }
  const float shift = M + logf(S);
  const int v = b * 256 + t;
  if (v < kV) logits[v] -= shift;
  const float invZ = 1.f / Z[0];
  if (b < 4) o_ctx[b * 256 + t] = ctx_ws[b * 256 + t] * invZ;
  else if (b < 20) o_attn[(b - 4) * 256 + t] = wexp[(b - 4) * 256 + t] * invZ;
}

extern "C" void kernel_launch(void* const* d_in, const int* in_sizes, int n_in,
                              void* d_out, int out_size, void* d_ws,
                              size_t ws_size, hipStream_t stream) {
  const int* tok = (const int*)d_in[0];
  const float* last_ctx = (const float*)d_in[1];
  const float* hidden = (const float*)d_in[2];
  const float* enc = (const float*)d_in[3];
  const float* emb = (const float*)d_in[4];
  const float* attn_W = (const float*)d_in[5];
  // d_in[6] attn_b: uniform shift of the energies, cancels in the softmax.
  const float* Wih0 = (const float*)d_in[7];
  const float* Whh0 = (const float*)d_in[8];
  const float* bih0 = (const float*)d_in[9];
  const float* bhh0 = (const float*)d_in[10];
  const float* Wih1 = (const float*)d_in[11];
  const float* Whh1 = (const float*)d_in[12];
  const float* bih1 = (const float*)d_in[13];
  const float* bhh1 = (const float*)d_in[14];
  const float* out_W = (const float*)d_in[15];
  const float* out_b = (const float*)d_in[16];

  float* out = (float*)d_out;
  float* o_logits = out;                 // [0, V)
  float* o_ctx = out + kV;               // [V, V+H)
  float* o_h0 = out + kV + kH;           // new_hidden[0]
  float* o_h1 = out + kV + 2 * kH;       // new_hidden[1]
  float* o_attn = out + kV + 3 * kH;     // [.., +S)

  // d_out sub-offsets are 4B-but-not-16B aligned (V % 4 == 1), so keep
  // 16B-aligned working copies of intermediates in the workspace.
  float* ws = (float*)d_ws;
  float* ws_u = ws;                      // 1024
  float* ws_h0 = ws + 1024;              // 1024
  float* ws_h1 = ws + 2048;              // 1024
  float* ws_ctx = ws + 3072;             // 1024 (unnormalized ctx accum)
  float* ws_attn = ws + 4096;            // 4096 (unnormalized exp weights)
  float* ws_part = ws + 8192;            // 2*kLogBBlocks = 4096
  float* ws_z = ws + 12288;              // 1 (+pad) softmax normalizer

  gru_kernel<<<kH, 256, 0, stream>>>(tok, emb, nullptr, last_ctx, hidden, Wih0,
                                     Whh0, bih0, bhh0, ws_h0, o_h0, ws_u,
                                     ws_ctx, ws_z);
  gru_kernel<<<kH, 256, 0, stream>>>(nullptr, nullptr, ws_h0, nullptr,
                                     hidden + kH, Wih1, Whh1, bih1, bhh1,
                                     ws_h1, o_h1, nullptr, nullptr, nullptr);
  attnu_logitsA_kernel<<<128 + kLogABlocks, 256, 0, stream>>>(
      attn_W, ws_h1, ws_u, out_W, out_b, o_logits);
  attn_fused_kernel<<<256, 256, 0, stream>>>(enc, ws_u, ws_attn, ws_ctx,
                                             ws_z);
  logitsB_kernel<<<kLogBBlocks, 256, 0, stream>>>(out_W, ws_ctx, ws_z,
                                                  o_logits, ws_part);
  finalize_kernel<<<(kV + 255) / 256, 256, 0, stream>>>(
      o_logits, ws_part, ws_ctx, ws_attn, ws_z, o_ctx, o_attn);
}

// Round 15
// 119.654 us; speedup vs baseline: 1.0202x; 1.0202x over previous
//
#include <hip/hip_runtime.h>
#include <math.h>

static constexpr int kH = 1024;
static constexpr int kV = 50257;
static constexpr int kS = 4096;
static constexpr int kLogABlocks = (kV + 3) / 4;   // 12565 (4 rows/block)
static constexpr int kLogBBlocks = 1024;           // wave-strided, 4096 waves
static constexpr float kEShift = 30.f;             // uniform softmax shift

__device__ __forceinline__ float wred_sum(float v) {
#pragma unroll
  for (int o = 32; o > 0; o >>= 1) v += __shfl_down(v, o, 64);
  return v;
}
__device__ __forceinline__ float wred_sum_all(float v) {
#pragma unroll
  for (int o = 32; o > 0; o >>= 1) v += __shfl_xor(v, o, 64);
  return v;
}

// One block per output element i of the GRU cell.
// If tok != nullptr: x = [emb[tok[0]], xb] (width 2H), else x = xa (width H).
// Blocks 0..8 zero the atomic accumulators zu/zc/zz when zu != nullptr.
__global__ __launch_bounds__(256) void gru_kernel(
    const int* __restrict__ tok, const float* __restrict__ emb,
    const float* __restrict__ xa, const float* __restrict__ xb,
    const float* __restrict__ hprev,
    const float* __restrict__ Wih, const float* __restrict__ Whh,
    const float* __restrict__ bih, const float* __restrict__ bhh,
    float* __restrict__ hout, float* __restrict__ hout2,
    float* __restrict__ zu, float* __restrict__ zc, float* __restrict__ zz) {
  const int i = blockIdx.x;
  const int t = threadIdx.x;
  const int lane = t & 63, wid = t >> 6;

  if (zu) {
    if (i < 4) zu[i * 256 + t] = 0.f;
    else if (i < 8) zc[(i - 4) * 256 + t] = 0.f;
    else if (i == 8 && t == 0) zz[0] = 0.f;
  }

  const float* xrow = tok ? (emb + (size_t)tok[0] * kH) : xa;
  const int nk4 = tok ? 512 : 256;         // float4 count of x
  const size_t xw = tok ? (size_t)(2 * kH) : (size_t)kH;

  const float4* X0 = (const float4*)xrow;
  const float4* X1 = (const float4*)xb;
  const float4* Wr = (const float4*)(Wih + (size_t)i * xw);
  const float4* Wz = (const float4*)(Wih + (size_t)(kH + i) * xw);
  const float4* Wn = (const float4*)(Wih + (size_t)(2 * kH + i) * xw);
  const float4* Ur = (const float4*)(Whh + (size_t)i * kH);
  const float4* Uz = (const float4*)(Whh + (size_t)(kH + i) * kH);
  const float4* Un = (const float4*)(Whh + (size_t)(2 * kH + i) * kH);
  const float4* Hp = (const float4*)hprev;

  float ar = 0.f, az = 0.f, an = 0.f, br = 0.f, bz = 0.f, bn = 0.f;
  for (int k = t; k < nk4; k += 256) {
    const float4 x = (k < 256) ? X0[k] : X1[k - 256];
    float4 w;
    w = Wr[k]; ar += w.x * x.x + w.y * x.y + w.z * x.z + w.w * x.w;
    w = Wz[k]; az += w.x * x.x + w.y * x.y + w.z * x.z + w.w * x.w;
    w = Wn[k]; an += w.x * x.x + w.y * x.y + w.z * x.z + w.w * x.w;
  }
  {
    const float4 h = Hp[t];
    float4 w;
    w = Ur[t]; br += w.x * h.x + w.y * h.y + w.z * h.z + w.w * h.w;
    w = Uz[t]; bz += w.x * h.x + w.y * h.y + w.z * h.z + w.w * h.w;
    w = Un[t]; bn += w.x * h.x + w.y * h.y + w.z * h.z + w.w * h.w;
  }
  ar = wred_sum(ar); az = wred_sum(az); an = wred_sum(an);
  br = wred_sum(br); bz = wred_sum(bz); bn = wred_sum(bn);
  __shared__ float red[6][4];
  if (lane == 0) {
    red[0][wid] = ar; red[1][wid] = az; red[2][wid] = an;
    red[3][wid] = br; red[4][wid] = bz; red[5][wid] = bn;
  }
  __syncthreads();
  if (t == 0) {
    const float s0 = red[0][0] + red[0][1] + red[0][2] + red[0][3];
    const float s1 = red[1][0] + red[1][1] + red[1][2] + red[1][3];
    const float s2 = red[2][0] + red[2][1] + red[2][2] + red[2][3];
    const float s3 = red[3][0] + red[3][1] + red[3][2] + red[3][3];
    const float s4 = red[4][0] + red[4][1] + red[4][2] + red[4][3];
    const float s5 = red[5][0] + red[5][1] + red[5][2] + red[5][3];
    const float r = 1.f / (1.f + expf(-((s0 + bih[i]) + (s3 + bhh[i]))));
    const float z = 1.f / (1.f + expf(-((s1 + bih[kH + i]) + (s4 + bhh[kH + i]))));
    const float n = tanhf((s2 + bih[2 * kH + i]) + r * (s5 + bhh[2 * kH + i]));
    const float h = (1.f - z) * n + z * hprev[i];
    hout[i] = h;
    hout2[i] = h;
  }
}

// Fused: blocks 0..127 compute u = attn_W^T h1 (atomics into u);
// blocks 128.. compute logitsA[v] = dot(out_W[v, 0:H], h1) + out_b[v],
// 4 consecutive rows per block, one wave per row (one-shot, contiguous).
__global__ __launch_bounds__(256) void attnu_logitsA_kernel(
    const float* __restrict__ attn_W, const float* __restrict__ h1,
    float* __restrict__ u, const float* __restrict__ out_W,
    const float* __restrict__ out_b, float* __restrict__ logits) {
  const int b = blockIdx.x;
  const int t = threadIdx.x;
  if (b < 128) {
    const int j0 = b * 8;
    const float4* W4 = (const float4*)attn_W;
    float4 acc = make_float4(0.f, 0.f, 0.f, 0.f);
#pragma unroll
    for (int j = j0; j < j0 + 8; ++j) {
      const float hj = h1[j];
      const float4 w = W4[(size_t)j * 256 + t];
      acc.x += hj * w.x; acc.y += hj * w.y;
      acc.z += hj * w.z; acc.w += hj * w.w;
    }
    atomicAdd(&u[4 * t + 0], acc.x);
    atomicAdd(&u[4 * t + 1], acc.y);
    atomicAdd(&u[4 * t + 2], acc.z);
    atomicAdd(&u[4 * t + 3], acc.w);
    return;
  }
  const int lane = t & 63;
  const int v = (b - 128) * 4 + (t >> 6);
  if (v >= kV) return;
  const float4* W = (const float4*)(out_W + (size_t)v * (2 * kH));
  const float4* X0 = (const float4*)h1;
  float acc = 0.f;
#pragma unroll
  for (int k = lane; k < 256; k += 64) {
    const float4 w = W[k];
    const float4 x = X0[k];
    acc += w.x * x.x + w.y * x.y + w.z * x.z + w.w * x.w;
  }
  acc = wred_sum(acc);
  if (lane == 0) logits[v] = acc + out_b[v];
}

// Fused attention: 256 blocks x 4 waves x 4 rows. Per row s:
//   e_s = dot(enc[s], u);  w_s = exp(e_s - kEShift)   (uniform shift -> exact
//   cancellation in normalization; no global max pass needed)
// Reuses the enc row already in registers to accumulate unnormalized
// ctx += w_s * enc[s] (LDS-staged per wave, then global atomics) and Z.
__global__ __launch_bounds__(256) void attn_fused_kernel(
    const float* __restrict__ enc, const float* __restrict__ u,
    float* __restrict__ wexp, float* __restrict__ ctx, float* __restrict__ Z) {
  const int b = blockIdx.x;
  const int t = threadIdx.x;
  const int lane = t & 63, wid = t >> 6;
  __shared__ float cacc[4][kH];  // 16 KB: per-wave unnormalized ctx partials
  __shared__ float zred[4];

  const float4* U4 = (const float4*)u;
  float4 u4[4];
#pragma unroll
  for (int j = 0; j < 4; ++j) u4[j] = U4[lane + 64 * j];

  float4 c4[4];
#pragma unroll
  for (int j = 0; j < 4; ++j) c4[j] = make_float4(0.f, 0.f, 0.f, 0.f);
  float zp = 0.f;
  const int s0 = b * 16 + wid * 4;
#pragma unroll
  for (int r = 0; r < 4; ++r) {
    const int s = s0 + r;
    const float4* E = (const float4*)(enc + (size_t)s * kH);
    float4 e4[4];
    float acc = 0.f;
#pragma unroll
    for (int j = 0; j < 4; ++j) {
      e4[j] = E[lane + 64 * j];
      acc += e4[j].x * u4[j].x + e4[j].y * u4[j].y + e4[j].z * u4[j].z +
             e4[j].w * u4[j].w;
    }
    acc = wred_sum_all(acc);
    const float w = expf(acc - kEShift);
    if (lane == 0) { wexp[s] = w; zp += w; }
#pragma unroll
    for (int j = 0; j < 4; ++j) {
      c4[j].x += w * e4[j].x; c4[j].y += w * e4[j].y;
      c4[j].z += w * e4[j].z; c4[j].w += w * e4[j].w;
    }
  }
#pragma unroll
  for (int j = 0; j < 4; ++j)
    ((float4*)&cacc[wid][0])[lane + 64 * j] = c4[j];
  if (lane == 0) zred[wid] = zp;
  __syncthreads();
#pragma unroll
  for (int j = 0; j < 4; ++j) {
    const int idx = t + 256 * j;
    const float vsum =
        cacc[0][idx] + cacc[1][idx] + cacc[2][idx] + cacc[3][idx];
    atomicAdd(&ctx[idx], vsum);
  }
  if (t == 0) atomicAdd(Z, zred[0] + zred[1] + zred[2] + zred[3]);
}

// logitsB: logits[v] += invZ * dot(out_W[v, H:2H], ctx_unnorm), wave-strided
// rows (12-13 per wave), online LSE per wave -> one partial per block.
__global__ __launch_bounds__(256) void logitsB_kernel(
    const float* __restrict__ out_W, const float* __restrict__ ctx,
    const float* __restrict__ Z, float* __restrict__ logits,
    float* __restrict__ part) {
  const int b = blockIdx.x;
  const int t = threadIdx.x;
  const int lane = t & 63, wid = t >> 6;
  __shared__ float red[2][4];

  const float invZ = 1.f / Z[0];
  const float4* X1 = (const float4*)ctx;
  float4 x1[4];
#pragma unroll
  for (int j = 0; j < 4; ++j) x1[j] = X1[lane + 64 * j];

  float lm = -INFINITY, ls = 0.f;
  for (int v = b * 4 + wid; v < kV; v += kLogBBlocks * 4) {
    const float4* W = (const float4*)(out_W + (size_t)v * (2 * kH)) + 256;
    float acc1 = 0.f;
#pragma unroll
    for (int j = 0; j < 4; ++j) {
      const float4 w = W[lane + 64 * j];
      acc1 += w.x * x1[j].x + w.y * x1[j].y + w.z * x1[j].z + w.w * x1[j].w;
    }
    const float acc = wred_sum(acc1);
    if (lane == 0) {
      const float val = logits[v] + invZ * acc;
      logits[v] = val;
      const float M2 = fmaxf(lm, val);
      ls = ls * expf(lm - M2) + expf(val - M2);
      lm = M2;
    }
  }
  if (lane == 0) { red[0][wid] = lm; red[1][wid] = ls; }
  __syncthreads();
  if (t == 0) {
    float m = red[0][0], s = red[1][0];
#pragma unroll
    for (int w = 1; w < 4; ++w) {
      const float M2 = fmaxf(m, red[0][w]);
      s = s * expf(m - M2) + red[1][w] * expf(red[0][w] - M2);
      m = M2;
    }
    part[2 * b] = m;
    part[2 * b + 1] = s;
  }
}

// finalize: each block redundantly merges the 1024 LSE partials (8 KB),
// normalizes its 256 logits; blocks 0..3 write o_ctx = ctx*invZ;
// blocks 4..19 write o_attn = wexp*invZ.
__global__ __launch_bounds__(256) void finalize_kernel(
    float* __restrict__ logits, const float* __restrict__ part,
    const float* __restrict__ ctx_ws, const float* __restrict__ wexp,
    const float* __restrict__ Z, float* __restrict__ o_ctx,
    float* __restrict__ o_attn) {
  const int b = blockIdx.x;
  const int t = threadIdx.x;
  const int lane = t & 63, wid = t >> 6;
  __shared__ float red[2][4];

  float m = -INFINITY, s = 0.f;
  for (int i = t; i < kLogBBlocks; i += 256) {
    const float bm = part[2 * i], bs = part[2 * i + 1];
    const float M2 = fmaxf(m, bm);
    s = s * expf(m - M2) + bs * expf(bm - M2);
    m = M2;
  }
#pragma unroll
  for (int o = 32; o > 0; o >>= 1) {
    const float m2 = __shfl_down(m, o, 64);
    const float s2 = __shfl_down(s, o, 64);
    const float M2 = fmaxf(m, m2);
    s = s * expf(m - M2) + s2 * expf(m2 - M2);
    m = M2;
  }
  if (lane == 0) { red[0][wid] = m; red[1][wid] = s; }
  __syncthreads();
  float M = red[0][0], S = red[1][0];
#pragma unroll
  for (int w = 1; w < 4; ++w) {
    const float M2 = fmaxf(M, red[0][w]);
    S = S * expf(M - M2) + red[1][w] * expf(red[0][w] - M2);
    M = M2;
  }
  const float shift = M + logf(S);
  const int v = b * 256 + t;
  if (v < kV) logits[v] -= shift;
  const float invZ = 1.f / Z[0];
  if (b < 4) o_ctx[b * 256 + t] = ctx_ws[b * 256 + t] * invZ;
  else if (b < 20) o_attn[(b - 4) * 256 + t] = wexp[(b - 4) * 256 + t] * invZ;
}

extern "C" void kernel_launch(void* const* d_in, const int* in_sizes, int n_in,
                              void* d_out, int out_size, void* d_ws,
                              size_t ws_size, hipStream_t stream) {
  const int* tok = (const int*)d_in[0];
  const float* last_ctx = (const float*)d_in[1];
  const float* hidden = (const float*)d_in[2];
  const float* enc = (const float*)d_in[3];
  const float* emb = (const float*)d_in[4];
  const float* attn_W = (const float*)d_in[5];
  // d_in[6] attn_b: uniform shift of the energies, cancels in the softmax.
  const float* Wih0 = (const float*)d_in[7];
  const float* Whh0 = (const float*)d_in[8];
  const float* bih0 = (const float*)d_in[9];
  const float* bhh0 = (const float*)d_in[10];
  const float* Wih1 = (const float*)d_in[11];
  const float* Whh1 = (const float*)d_in[12];
  const float* bih1 = (const float*)d_in[13];
  const float* bhh1 = (const float*)d_in[14];
  const float* out_W = (const float*)d_in[15];
  const float* out_b = (const float*)d_in[16];

  float* out = (float*)d_out;
  float* o_logits = out;                 // [0, V)
  float* o_ctx = out + kV;               // [V, V+H)
  float* o_h0 = out + kV + kH;           // new_hidden[0]
  float* o_h1 = out + kV + 2 * kH;       // new_hidden[1]
  float* o_attn = out + kV + 3 * kH;     // [.., +S)

  // d_out sub-offsets are 4B-but-not-16B aligned (V % 4 == 1), so keep
  // 16B-aligned working copies of intermediates in the workspace.
  float* ws = (float*)d_ws;
  float* ws_u = ws;                      // 1024
  float* ws_h0 = ws + 1024;              // 1024
  float* ws_h1 = ws + 2048;              // 1024
  float* ws_ctx = ws + 3072;             // 1024 (unnormalized ctx accum)
  float* ws_attn = ws + 4096;            // 4096 (unnormalized exp weights)
  float* ws_part = ws + 8192;            // 2*kLogBBlocks
  float* ws_z = ws + 10240;              // 1 (+pad) softmax normalizer

  gru_kernel<<<kH, 256, 0, stream>>>(tok, emb, nullptr, last_ctx, hidden, Wih0,
                                     Whh0, bih0, bhh0, ws_h0, o_h0, ws_u,
                                     ws_ctx, ws_z);
  gru_kernel<<<kH, 256, 0, stream>>>(nullptr, nullptr, ws_h0, nullptr,
                                     hidden + kH, Wih1, Whh1, bih1, bhh1,
                                     ws_h1, o_h1, nullptr, nullptr, nullptr);
  attnu_logitsA_kernel<<<128 + kLogABlocks, 256, 0, stream>>>(
      attn_W, ws_h1, ws_u, out_W, out_b, o_logits);
  attn_fused_kernel<<<256, 256, 0, stream>>>(enc, ws_u, ws_attn, ws_ctx,
                                             ws_z);
  logitsB_kernel<<<kLogBBlocks, 256, 0, stream>>>(out_W, ws_ctx, ws_z,
                                                  o_logits, ws_part);
  finalize_kernel<<<(kV + 255) / 256, 256, 0, stream>>>(
      o_logits, ws_part, ws_ctx, ws_attn, ws_z, o_ctx, o_attn);
}